// Round 19
// baseline (177.010 us; speedup 1.0000x reference)
//
#include <hip/hip_runtime.h>
#include <hip/hip_bf16.h>

typedef unsigned short u16;
typedef __attribute__((ext_vector_type(8))) short short8;
typedef __attribute__((ext_vector_type(4))) float f32x4;

#define VMC2 asm volatile("s_waitcnt vmcnt(2)" ::: "memory")
#define VMC0 asm volatile("s_waitcnt vmcnt(0)" ::: "memory")

__device__ __forceinline__ float b2f(u16 u){
    unsigned v = ((unsigned)u) << 16; float f; __builtin_memcpy(&f, &v, 4); return f;
}
__device__ __forceinline__ u16 f2b(float f){
    unsigned v; __builtin_memcpy(&v, &f, 4);
    v += 0x7fffu + ((v >> 16) & 1u);
    return (u16)(v >> 16);
}
__device__ __forceinline__ unsigned pk2(float lo, float hi){
    unsigned a, b; __builtin_memcpy(&a, &lo, 4); __builtin_memcpy(&b, &hi, 4);
    return __builtin_amdgcn_perm(b + 0x8000u, a + 0x8000u, 0x07060302u);
}
__device__ __forceinline__ float ex2(float x){
    float r; asm("v_exp_f32 %0, %1" : "=v"(r) : "v"(x)); return r;
}
__device__ __forceinline__ float rcp(float x){
    float r; asm("v_rcp_f32 %0, %1" : "=v"(r) : "v"(x)); return r;
}
__device__ __forceinline__ void gload16(const void* g, void* l){
    __builtin_amdgcn_global_load_lds((const __attribute__((address_space(1))) unsigned int*)g,
                                     (__attribute__((address_space(3))) unsigned int*)l, 16, 0, 0);
}
__device__ __forceinline__ int swz(int row, int col){
    return row * 64 + (col ^ ((row & 7) << 3));
}

__global__ void cvtall_k(const float* __restrict__ x,
                         const float* __restrict__ wq, const float* __restrict__ wk,
                         const float* __restrict__ wv, const float* __restrict__ wp,
                         u16* __restrict__ xb, u16* __restrict__ wb)
{
    const int blk = blockIdx.x;
    const float* src; u16* dst;
    if (blk < 8192) {
        src = x + (size_t)blk * 1024; dst = xb + (size_t)blk * 1024;
    } else {
        const int m = (blk - 8192) >> 10, r = (blk - 8192) & 1023;
        const float* w = (m == 0) ? wq : (m == 1) ? wk : (m == 2) ? wv : wp;
        src = w + (size_t)r * 1024; dst = wb + ((size_t)m << 20) + (size_t)r * 1024;
    }
    const int i = threadIdx.x * 4;
    float4 v = *(const float4*)&src[i];
    ushort4 o;
    o.x = f2b(v.x); o.y = f2b(v.y); o.z = f2b(v.z); o.w = f2b(v.w);
    *(ushort4*)&dst[i] = o;
}

// QKV GEMM, persistent-pair: grid (64,12)=768 blocks=3/CU, zero tail.
__global__ __launch_bounds__(256, 2)
void gemm3_k(const u16* __restrict__ A, const u16* __restrict__ Wb,
             const float* __restrict__ b0, const float* __restrict__ b1,
             const float* __restrict__ b2,
             u16* __restrict__ C0, u16* __restrict__ C1, u16* __restrict__ C2)
{
    __shared__ u16 As[128 * 64];
    __shared__ u16 Bs[128 * 64];
    const int K = 1024, N = 1024;
    const int tid  = threadIdx.x;
    const int wave = tid >> 6, lane = tid & 63;
    const int lg = lane >> 4, lr = lane & 15;
    const int m0 = blockIdx.x * 128;
    const int wm = (wave >> 1) * 64, wn = (wave & 1) * 64;

    const int srow = tid >> 3;
    const int sc8  = ((tid & 7) ^ (srow & 7)) * 8;
    const u16* aG = A + (size_t)(m0 + srow) * K + sc8;
    char* asBase = (char*)As + wave * 1024;
    char* bsBase = (char*)Bs + wave * 1024;
    const size_t rstep = (size_t)32 * K;

#pragma unroll 1
    for (int p = 0; p < 2; ++p) {
        const int y   = (int)blockIdx.y + p * 12;
        const int mat = y >> 3;
        const int n0  = (y & 7) * 128;
        const u16* W = Wb + ((size_t)mat << 20);
        const float* bias = (mat == 0) ? b0 : (mat == 1) ? b1 : b2;
        u16* C = (mat == 0) ? C0 : (mat == 1) ? C1 : C2;
        const u16* bG = W + (size_t)(n0 + srow) * K + sc8;

        f32x4 acc[4][4] = {};

        for (int kt = 0; kt < K; kt += 64) {
#pragma unroll
            for (int i = 0; i < 4; ++i) {
                gload16(aG + kt + i * rstep, asBase + i * 4096);
                gload16(bG + kt + i * rstep, bsBase + i * 4096);
            }
            __syncthreads();

#pragma unroll
            for (int s = 0; s < 2; ++s) {
                short8 a[4], b[4];
#pragma unroll
                for (int i = 0; i < 4; ++i) a[i] = *(const short8*)&As[swz(wm + i*16 + lr, s*32 + lg*8)];
#pragma unroll
                for (int j = 0; j < 4; ++j) b[j] = *(const short8*)&Bs[swz(wn + j*16 + lr, s*32 + lg*8)];
                __builtin_amdgcn_s_setprio(1);
#pragma unroll
                for (int i = 0; i < 4; ++i)
#pragma unroll
                    for (int j = 0; j < 4; ++j)
                        acc[i][j] = __builtin_amdgcn_mfma_f32_16x16x32_bf16(a[i], b[j], acc[i][j], 0, 0, 0);
                __builtin_amdgcn_s_setprio(0);
            }
            __syncthreads();
        }

#pragma unroll
        for (int j = 0; j < 4; ++j) {
            const int cn = n0 + wn + j*16 + lr;
            const float bv = bias[cn];
#pragma unroll
            for (int i = 0; i < 4; ++i) {
                const int cm = m0 + wm + i*16 + lg*4;
#pragma unroll
                for (int r = 0; r < 4; ++r)
                    C[(size_t)(cm + r) * N + cn] = f2b(acc[i][j][r] + bv);
            }
        }
    }
}

__global__ __launch_bounds__(256, 2)
void gemm_k(const u16* __restrict__ A, const u16* __restrict__ W,
            const float* __restrict__ bias, u16* __restrict__ C,
            int M, int N, int K)
{
    __shared__ u16 As[128 * 64];
    __shared__ u16 Bs[128 * 64];
    const int tid  = threadIdx.x;
    const int wave = tid >> 6, lane = tid & 63;
    const int lg = lane >> 4, lr = lane & 15;
    const int m0 = blockIdx.x * 128, n0 = blockIdx.y * 128;
    const int wm = (wave >> 1) * 64, wn = (wave & 1) * 64;

    const int srow = tid >> 3;
    const int sc8  = ((tid & 7) ^ (srow & 7)) * 8;
    const u16* aG = A + (size_t)(m0 + srow) * K + sc8;
    const u16* bG = W + (size_t)(n0 + srow) * K + sc8;
    char* asBase = (char*)As + wave * 1024;
    char* bsBase = (char*)Bs + wave * 1024;
    const size_t rstep = (size_t)32 * K;

    f32x4 acc[4][4] = {};

    for (int kt = 0; kt < K; kt += 64) {
#pragma unroll
        for (int i = 0; i < 4; ++i) {
            gload16(aG + kt + i * rstep, asBase + i * 4096);
            gload16(bG + kt + i * rstep, bsBase + i * 4096);
        }
        __syncthreads();

#pragma unroll
        for (int s = 0; s < 2; ++s) {
            short8 a[4], b[4];
#pragma unroll
            for (int i = 0; i < 4; ++i) a[i] = *(const short8*)&As[swz(wm + i*16 + lr, s*32 + lg*8)];
#pragma unroll
            for (int j = 0; j < 4; ++j) b[j] = *(const short8*)&Bs[swz(wn + j*16 + lr, s*32 + lg*8)];
            __builtin_amdgcn_s_setprio(1);
#pragma unroll
            for (int i = 0; i < 4; ++i)
#pragma unroll
                for (int j = 0; j < 4; ++j)
                    acc[i][j] = __builtin_amdgcn_mfma_f32_16x16x32_bf16(a[i], b[j], acc[i][j], 0, 0, 0);
            __builtin_amdgcn_s_setprio(0);
        }
        __syncthreads();
    }

#pragma unroll
    for (int j = 0; j < 4; ++j) {
        const int cn = n0 + wn + j*16 + lr;
        const float bv = bias[cn];
#pragma unroll
        for (int i = 0; i < 4; ++i) {
            const int cm = m0 + wm + i*16 + lg*4;
#pragma unroll
            for (int r = 0; r < 4; ++r)
                C[(size_t)(cm + r) * N + cn] = f2b(acc[i][j][r] + bv);
        }
    }
}

__global__ void ln3_k(u16* D0, u16* D1, const u16* __restrict__ Sv,
                      const float* __restrict__ g_q, const float* __restrict__ be_q,
                      const float* __restrict__ g_k, const float* __restrict__ be_k,
                      const float* __restrict__ g_v, const float* __restrict__ be_v,
                      float* __restrict__ Vf)
{
    __shared__ float red[8];
    const int which = blockIdx.y;
    const u16* src = (which == 0) ? D0 : (which == 1) ? D1 : Sv;
    const float* g  = (which == 0) ? g_q  : (which == 1) ? g_k  : g_v;
    const float* be = (which == 0) ? be_q : (which == 1) ? be_k : be_v;
    const float scale = (which == 0) ? 0.125f * 1.4426950408889634f : 1.0f;

    const int row = blockIdx.x;
    const int tid = threadIdx.x;
    const int lane = tid & 63, wave = tid >> 6;
    ushort4 v = *(const ushort4*)&src[(size_t)row * 1024 + tid * 4];
    float f[4] = { b2f(v.x), b2f(v.y), b2f(v.z), b2f(v.w) };
    float s  = f[0] + f[1] + f[2] + f[3];
    float ss = f[0]*f[0] + f[1]*f[1] + f[2]*f[2] + f[3]*f[3];
#pragma unroll
    for (int off = 32; off; off >>= 1) { s += __shfl_down(s, off); ss += __shfl_down(ss, off); }
    if (lane == 0) { red[wave] = s; red[4 + wave] = ss; }
    __syncthreads();
    s  = red[0] + red[1] + red[2] + red[3];
    ss = red[4] + red[5] + red[6] + red[7];
    const float mean = s * (1.0f / 1024.0f);
    const float var  = fmaxf(ss * (1.0f / 1024.0f) - mean * mean, 0.0f);
    const float rs   = rsqrtf(var + 1e-5f);
    float o[4];
#pragma unroll
    for (int k = 0; k < 4; ++k) {
        const int e = tid * 4 + k;
        o[k] = ((f[k] - mean) * rs * g[e] + be[e]) * scale;
    }
    if (which == 2) {
        const int b = row >> 11, sIdx = row & 2047;
        const int h = tid >> 4, hd = (tid * 4) & 63;
        float4 ov = { o[0], o[1], o[2], o[3] };
        *(float4*)&Vf[(((size_t)(b * 16 + h) * 2048 + sIdx) << 6) + hd] = ov;
    } else {
        u16* dst = (which == 0) ? D0 : D1;
        ushort4 ov; ov.x = f2b(o[0]); ov.y = f2b(o[1]); ov.z = f2b(o[2]); ov.w = f2b(o[3]);
        *(ushort4*)&dst[(size_t)row * 1024 + tid * 4] = ov;
    }
}

__global__ void lnf_k(const u16* __restrict__ src, const float* __restrict__ g,
                      const float* __restrict__ be, float* __restrict__ dst)
{
    __shared__ float red[8];
    const int row = blockIdx.x;
    const int tid = threadIdx.x;
    const int lane = tid & 63, wave = tid >> 6;
    ushort4 v = *(const ushort4*)&src[(size_t)row * 1024 + tid * 4];
    float f[4] = { b2f(v.x), b2f(v.y), b2f(v.z), b2f(v.w) };
    float s  = f[0] + f[1] + f[2] + f[3];
    float ss = f[0]*f[0] + f[1]*f[1] + f[2]*f[2] + f[3]*f[3];
#pragma unroll
    for (int off = 32; off; off >>= 1) { s += __shfl_down(s, off); ss += __shfl_down(ss, off); }
    if (lane == 0) { red[wave] = s; red[4 + wave] = ss; }
    __syncthreads();
    s  = red[0] + red[1] + red[2] + red[3];
    ss = red[4] + red[5] + red[6] + red[7];
    const float mean = s * (1.0f / 1024.0f);
    const float var  = fmaxf(ss * (1.0f / 1024.0f) - mean * mean, 0.0f);
    const float rs   = rsqrtf(var + 1e-5f);
    float4 ov;
    ov.x = (f[0] - mean) * rs * g[tid*4+0] + be[tid*4+0];
    ov.y = (f[1] - mean) * rs * g[tid*4+1] + be[tid*4+1];
    ov.z = (f[2] - mean) * rs * g[tid*4+2] + be[tid*4+2];
    ov.w = (f[3] - mean) * rs * g[tid*4+3] + be[tid*4+3];
    *(float4*)&dst[(size_t)row * 1024 + tid * 4] = ov;
}

__global__ void vtr_k(const float* __restrict__ Vf, u16* __restrict__ Vt)
{
    __shared__ float T[64 * 65];
    const int bh = blockIdx.x >> 5, st = blockIdx.x & 31;
    const int tid = threadIdx.x;
    const float* src = Vf + (size_t)bh * 2048 * 64 + (size_t)st * 64 * 64;
#pragma unroll
    for (int it = 0; it < 4; ++it) {
        const int fid = tid + it * 256;
        const int r = fid >> 4, c4 = fid & 15;
        float4 v = *(const float4*)&src[r * 64 + c4 * 4];
        T[r * 65 + c4*4 + 0] = v.x;
        T[r * 65 + c4*4 + 1] = v.y;
        T[r * 65 + c4*4 + 2] = v.z;
        T[r * 65 + c4*4 + 3] = v.w;
    }
    __syncthreads();
    u16* dst = Vt + (size_t)bh * 64 * 2048 + (size_t)st * 64;
#pragma unroll
    for (int it = 0; it < 2; ++it) {
        const int oid = tid + it * 256;
        const int hd = oid >> 3, ch = oid & 7;
        u16 tmp[8];
#pragma unroll
        for (int j = 0; j < 8; ++j) tmp[j] = f2b(T[(ch * 8 + j) * 65 + hd]);
        const int base = 32 * (ch >> 2) + 4 * ((ch >> 1) & 1);
        const int p0 = base + 8 * ((2 * ch + 0) & 3);
        const int p1 = base + 8 * ((2 * ch + 1) & 3);
        ushort4 lo = { tmp[0], tmp[1], tmp[2], tmp[3] };
        ushort4 hi = { tmp[4], tmp[5], tmp[6], tmp[7] };
        *(ushort4*)&dst[(size_t)hd * 2048 + p0] = lo;
        *(ushort4*)&dst[(size_t)hd * 2048 + p1] = hi;
    }
}

// Causal flash attention, paired q-tiles {x, 15-x}: grid (8,64)=512 uniform
// blocks (34 kv-iters each), all resident (3/CU LDS capacity), zero tail.
__global__ __launch_bounds__(512, 4)
void attn_k(const u16* __restrict__ Qf, const u16* __restrict__ Kf,
            const u16* __restrict__ Vt, u16* __restrict__ O)
{
    __shared__ u16 Lds[24576];
    const int lin = (int)blockIdx.x + (int)blockIdx.y * 8;
    const int xcd = lin & 7, idx = lin >> 3;
    const int bh  = xcd * 8 + (idx & 7);
    const int xpr = idx >> 3;                 // 0..7
    const int b = bh >> 4, h = bh & 15;
    const int tid = threadIdx.x, wave = tid >> 6, lane = tid & 63;
    const int lg = lane >> 4, lr = lane & 15;
    const u16* Qbh = Qf + ((size_t)b * 2048) * 1024 + h * 64;
    const u16* Kbh = Kf + ((size_t)b * 2048) * 1024 + h * 64;
    const u16* Vbh = Vt + (size_t)bh * 64 * 2048;
    u16* Obh = O + ((size_t)b * 2048) * 1024 + h * 64;

    const int kro0 = swz(lr, lg * 8) * 2;
    const int kro1 = swz(lr, 32 + lg * 8) * 2;
    const int vro0 = 8192 + kro0;
    const int vro1 = 8192 + kro1;
    const char* ldsB = (const char*)Lds;

    const int sr = tid >> 3;
    const int sc8 = ((tid & 7) ^ (sr & 7)) * 8;
    const int stKo = wave * 1024;

    const short s1 = (short)0x3F80;
    const short8 ones = { s1,s1,s1,s1,s1,s1,s1,s1 };

    const int qts[2] = { 15 - xpr, xpr };     // big half first

#pragma unroll 1
    for (int hf = 0; hf < 2; ++hf) {
        const int qt = qts[hf];
        const int q0w  = qt * 128 + wave * 16;
        const int qrow = q0w + lr;
        const short8 qf0 = *(const short8*)&Qbh[(size_t)qrow * 1024 + lg * 8];
        const short8 qf1 = *(const short8*)&Qbh[(size_t)qrow * 1024 + 32 + lg * 8];

        const int nkv    = 2 * qt + 2;
        const int diagkv = q0w >> 6;

        const u16* kg = Kbh + (size_t)sr * 1024 + sc8;
        const u16* vg = Vbh + (size_t)sr * 2048 + sc8;

        f32x4 oacc[4] = {};
        f32x4 lacc = { 0.f, 0.f, 0.f, 0.f };

        gload16(kg,          (char*)Lds + stKo);
        gload16(vg,          (char*)Lds + 8192 + stKo);
        gload16(kg + 65536,  (char*)Lds + 16384 + stKo);
        gload16(vg + 64,     (char*)Lds + 16384 + 8192 + stKo);
        kg += 131072; vg += 128;
        VMC2;
        __builtin_amdgcn_s_barrier();

        int ro = 0;
        for (int kv = 0; kv < nkv; ++kv) {
            const bool doStage = (kv + 2 < nkv);
            if (doStage) {
                int so = ro + 32768; if (so >= 49152) so -= 49152;
                gload16(kg, (char*)Lds + so + stKo);
                gload16(vg, (char*)Lds + so + 8192 + stKo);
                kg += 65536; vg += 64;
            }

            if (kv <= diagkv) {
                const char* kp0 = ldsB + (ro + kro0);
                const char* kp1 = ldsB + (ro + kro1);

                f32x4 sacc[4];
                __builtin_amdgcn_s_setprio(1);
#pragma unroll
                for (int c = 0; c < 4; ++c) {
                    const short8 k0 = *(const short8*)(kp0 + c * 2048);
                    const short8 k1 = *(const short8*)(kp1 + c * 2048);
                    f32x4 z = { 0.f, 0.f, 0.f, 0.f };
                    z = __builtin_amdgcn_mfma_f32_16x16x32_bf16(k0, qf0, z, 0, 0, 0);
                    z = __builtin_amdgcn_mfma_f32_16x16x32_bf16(k1, qf1, z, 0, 0, 0);
                    sacc[c] = z;
                }
                __builtin_amdgcn_s_setprio(0);

                if (kv == diagkv) {
                    const int kbase = kv * 64 + 4 * lg;
#pragma unroll
                    for (int c = 0; c < 4; ++c)
#pragma unroll
                        for (int r = 0; r < 4; ++r)
                            if (kbase + c * 16 + r > qrow) sacc[c][r] = -1e30f;
                }

#pragma unroll
                for (int c = 0; c < 4; ++c)
#pragma unroll
                    for (int r = 0; r < 4; ++r) sacc[c][r] = ex2(sacc[c][r]);

                const char* vp0 = ldsB + (ro + vro0);
                const char* vp1 = ldsB + (ro + vro1);
#pragma unroll
                for (int m2 = 0; m2 < 2; ++m2) {
                    union { unsigned w[4]; short8 v; } pa;
                    pa.w[0] = pk2(sacc[2*m2][0],   sacc[2*m2][1]);
                    pa.w[1] = pk2(sacc[2*m2][2],   sacc[2*m2][3]);
                    pa.w[2] = pk2(sacc[2*m2+1][0], sacc[2*m2+1][1]);
                    pa.w[3] = pk2(sacc[2*m2+1][2], sacc[2*m2+1][3]);
                    const char* vp = m2 ? vp1 : vp0;
                    __builtin_amdgcn_s_setprio(1);
                    lacc = __builtin_amdgcn_mfma_f32_16x16x32_bf16(pa.v, ones, lacc, 0, 0, 0);
#pragma unroll
                    for (int c2 = 0; c2 < 4; ++c2) {
                        const short8 vb = *(const short8*)(vp + c2 * 2048);
                        oacc[c2] = __builtin_amdgcn_mfma_f32_16x16x32_bf16(pa.v, vb, oacc[c2], 0, 0, 0);
                    }
                    __builtin_amdgcn_s_setprio(0);
                }
            }

            if (kv + 1 < nkv) {
                if (doStage) { VMC2; }
                else        { VMC0; }
                __builtin_amdgcn_s_barrier();
            }
            ro += 16384; if (ro == 49152) ro = 0;
        }
        VMC0;
        __builtin_amdgcn_s_barrier();          // LDS quiesced before next half

        float lo[4];
#pragma unroll
        for (int r = 0; r < 4; ++r) lo[r] = rcp(lacc[r]);
#pragma unroll
        for (int c2 = 0; c2 < 4; ++c2)
#pragma unroll
            for (int r = 0; r < 4; ++r) {
                const float ov = oacc[c2][r] * lo[r];
                Obh[(size_t)(q0w + 4 * lg + r) * 1024 + c2 * 16 + lr] = f2b(ov);
            }
    }
}

extern "C" void kernel_launch(void* const* d_in, const int* in_sizes, int n_in,
                              void* d_out, int out_size, void* d_ws, size_t ws_size,
                              hipStream_t stream)
{
    (void)in_sizes; (void)n_in; (void)out_size; (void)ws_size;
    const float* x   = (const float*)d_in[0];
    const float* wq  = (const float*)d_in[1];  const float* bq   = (const float*)d_in[2];
    const float* wk  = (const float*)d_in[3];  const float* bk   = (const float*)d_in[4];
    const float* wv  = (const float*)d_in[5];  const float* bv   = (const float*)d_in[6];
    const float* wp  = (const float*)d_in[7];  const float* bp   = (const float*)d_in[8];
    const float* g_q = (const float*)d_in[9];  const float* be_q = (const float*)d_in[10];
    const float* g_k = (const float*)d_in[11]; const float* be_k = (const float*)d_in[12];
    const float* g_v = (const float*)d_in[13]; const float* be_v = (const float*)d_in[14];
    const float* g_p = (const float*)d_in[15]; const float* be_p = (const float*)d_in[16];

    float* outF = (float*)d_out;
    float* Vf   = outF + 8388608;
    u16* D0 = (u16*)d_out;
    u16* D1 = (u16*)d_out + 8388608;
    u16* xb = (u16*)d_out + 16777216;
    char* ws = (char*)d_ws;
    u16* S0  = (u16*)ws;
    u16* wb  = (u16*)(ws + 16777216);
    u16* wpb = wb + 3145728;

    const dim3 bb(256);
    cvtall_k<<<dim3(12288), bb, 0, stream>>>(x, wq, wk, wv, wp, xb, wb);
    gemm3_k<<<dim3(64, 12), bb, 0, stream>>>(xb, wb, bq, bk, bv, D0, D1, S0);
    ln3_k<<<dim3(8192, 3), bb, 0, stream>>>(D0, D1, S0, g_q, be_q, g_k, be_k, g_v, be_v, Vf);
    vtr_k<<<dim3(2048), bb, 0, stream>>>(Vf, S0);
    attn_k<<<dim3(8, 64), dim3(512), 0, stream>>>(D0, D1, S0, D0);
    gemm_k<<<dim3(64, 8), bb, 0, stream>>>(D0, wpb, bp, S0, 8192, 1024, 1024);
    lnf_k<<<dim3(8192), bb, 0, stream>>>(S0, g_p, be_p, outF);
}

// Round 20
// 175.012 us; speedup vs baseline: 1.0114x; 1.0114x over previous
//
#include <hip/hip_runtime.h>
#include <hip/hip_bf16.h>

typedef unsigned short u16;
typedef __attribute__((ext_vector_type(8))) short short8;
typedef __attribute__((ext_vector_type(4))) float f32x4;

#define VMC2 asm volatile("s_waitcnt vmcnt(2)" ::: "memory")
#define VMC0 asm volatile("s_waitcnt vmcnt(0)" ::: "memory")

__device__ __forceinline__ float b2f(u16 u){
    unsigned v = ((unsigned)u) << 16; float f; __builtin_memcpy(&f, &v, 4); return f;
}
__device__ __forceinline__ u16 f2b(float f){
    unsigned v; __builtin_memcpy(&v, &f, 4);
    v += 0x7fffu + ((v >> 16) & 1u);
    return (u16)(v >> 16);
}
__device__ __forceinline__ unsigned pk2(float lo, float hi){
    unsigned a, b; __builtin_memcpy(&a, &lo, 4); __builtin_memcpy(&b, &hi, 4);
    return __builtin_amdgcn_perm(b + 0x8000u, a + 0x8000u, 0x07060302u);
}
__device__ __forceinline__ float ex2(float x){
    float r; asm("v_exp_f32 %0, %1" : "=v"(r) : "v"(x)); return r;
}
__device__ __forceinline__ float rcp(float x){
    float r; asm("v_rcp_f32 %0, %1" : "=v"(r) : "v"(x)); return r;
}
__device__ __forceinline__ void gload16(const void* g, void* l){
    __builtin_amdgcn_global_load_lds((const __attribute__((address_space(1))) unsigned int*)g,
                                     (__attribute__((address_space(3))) unsigned int*)l, 16, 0, 0);
}
__device__ __forceinline__ int swz(int row, int col){
    return row * 64 + (col ^ ((row & 7) << 3));
}

__global__ void cvtall_k(const float* __restrict__ x,
                         const float* __restrict__ wq, const float* __restrict__ wk,
                         const float* __restrict__ wv, const float* __restrict__ wp,
                         u16* __restrict__ xb, u16* __restrict__ wb)
{
    const int blk = blockIdx.x;
    const float* src; u16* dst;
    if (blk < 8192) {
        src = x + (size_t)blk * 1024; dst = xb + (size_t)blk * 1024;
    } else {
        const int m = (blk - 8192) >> 10, r = (blk - 8192) & 1023;
        const float* w = (m == 0) ? wq : (m == 1) ? wk : (m == 2) ? wv : wp;
        src = w + (size_t)r * 1024; dst = wb + ((size_t)m << 20) + (size_t)r * 1024;
    }
    const int i = threadIdx.x * 4;
    float4 v = *(const float4*)&src[i];
    ushort4 o;
    o.x = f2b(v.x); o.y = f2b(v.y); o.z = f2b(v.z); o.w = f2b(v.w);
    *(ushort4*)&dst[i] = o;
}

// QKV GEMM, persistent-pair: grid (64,12)=768 blocks=3/CU, zero tail.
__global__ __launch_bounds__(256, 2)
void gemm3_k(const u16* __restrict__ A, const u16* __restrict__ Wb,
             const float* __restrict__ b0, const float* __restrict__ b1,
             const float* __restrict__ b2,
             u16* __restrict__ C0, u16* __restrict__ C1, u16* __restrict__ C2)
{
    __shared__ u16 As[128 * 64];
    __shared__ u16 Bs[128 * 64];
    const int K = 1024, N = 1024;
    const int tid  = threadIdx.x;
    const int wave = tid >> 6, lane = tid & 63;
    const int lg = lane >> 4, lr = lane & 15;
    const int m0 = blockIdx.x * 128;
    const int wm = (wave >> 1) * 64, wn = (wave & 1) * 64;

    const int srow = tid >> 3;
    const int sc8  = ((tid & 7) ^ (srow & 7)) * 8;
    const u16* aG = A + (size_t)(m0 + srow) * K + sc8;
    char* asBase = (char*)As + wave * 1024;
    char* bsBase = (char*)Bs + wave * 1024;
    const size_t rstep = (size_t)32 * K;

#pragma unroll 1
    for (int p = 0; p < 2; ++p) {
        const int y   = (int)blockIdx.y + p * 12;
        const int mat = y >> 3;
        const int n0  = (y & 7) * 128;
        const u16* W = Wb + ((size_t)mat << 20);
        const float* bias = (mat == 0) ? b0 : (mat == 1) ? b1 : b2;
        u16* C = (mat == 0) ? C0 : (mat == 1) ? C1 : C2;
        const u16* bG = W + (size_t)(n0 + srow) * K + sc8;

        f32x4 acc[4][4] = {};

        for (int kt = 0; kt < K; kt += 64) {
#pragma unroll
            for (int i = 0; i < 4; ++i) {
                gload16(aG + kt + i * rstep, asBase + i * 4096);
                gload16(bG + kt + i * rstep, bsBase + i * 4096);
            }
            __syncthreads();

#pragma unroll
            for (int s = 0; s < 2; ++s) {
                short8 a[4], b[4];
#pragma unroll
                for (int i = 0; i < 4; ++i) a[i] = *(const short8*)&As[swz(wm + i*16 + lr, s*32 + lg*8)];
#pragma unroll
                for (int j = 0; j < 4; ++j) b[j] = *(const short8*)&Bs[swz(wn + j*16 + lr, s*32 + lg*8)];
                __builtin_amdgcn_s_setprio(1);
#pragma unroll
                for (int i = 0; i < 4; ++i)
#pragma unroll
                    for (int j = 0; j < 4; ++j)
                        acc[i][j] = __builtin_amdgcn_mfma_f32_16x16x32_bf16(a[i], b[j], acc[i][j], 0, 0, 0);
                __builtin_amdgcn_s_setprio(0);
            }
            __syncthreads();
        }

#pragma unroll
        for (int j = 0; j < 4; ++j) {
            const int cn = n0 + wn + j*16 + lr;
            const float bv = bias[cn];
#pragma unroll
            for (int i = 0; i < 4; ++i) {
                const int cm = m0 + wm + i*16 + lg*4;
#pragma unroll
                for (int r = 0; r < 4; ++r)
                    C[(size_t)(cm + r) * N + cn] = f2b(acc[i][j][r] + bv);
            }
        }
    }
}

__global__ __launch_bounds__(256, 2)
void gemm_k(const u16* __restrict__ A, const u16* __restrict__ W,
            const float* __restrict__ bias, u16* __restrict__ C,
            int M, int N, int K)
{
    __shared__ u16 As[128 * 64];
    __shared__ u16 Bs[128 * 64];
    const int tid  = threadIdx.x;
    const int wave = tid >> 6, lane = tid & 63;
    const int lg = lane >> 4, lr = lane & 15;
    const int m0 = blockIdx.x * 128, n0 = blockIdx.y * 128;
    const int wm = (wave >> 1) * 64, wn = (wave & 1) * 64;

    const int srow = tid >> 3;
    const int sc8  = ((tid & 7) ^ (srow & 7)) * 8;
    const u16* aG = A + (size_t)(m0 + srow) * K + sc8;
    const u16* bG = W + (size_t)(n0 + srow) * K + sc8;
    char* asBase = (char*)As + wave * 1024;
    char* bsBase = (char*)Bs + wave * 1024;
    const size_t rstep = (size_t)32 * K;

    f32x4 acc[4][4] = {};

    for (int kt = 0; kt < K; kt += 64) {
#pragma unroll
        for (int i = 0; i < 4; ++i) {
            gload16(aG + kt + i * rstep, asBase + i * 4096);
            gload16(bG + kt + i * rstep, bsBase + i * 4096);
        }
        __syncthreads();

#pragma unroll
        for (int s = 0; s < 2; ++s) {
            short8 a[4], b[4];
#pragma unroll
            for (int i = 0; i < 4; ++i) a[i] = *(const short8*)&As[swz(wm + i*16 + lr, s*32 + lg*8)];
#pragma unroll
            for (int j = 0; j < 4; ++j) b[j] = *(const short8*)&Bs[swz(wn + j*16 + lr, s*32 + lg*8)];
            __builtin_amdgcn_s_setprio(1);
#pragma unroll
            for (int i = 0; i < 4; ++i)
#pragma unroll
                for (int j = 0; j < 4; ++j)
                    acc[i][j] = __builtin_amdgcn_mfma_f32_16x16x32_bf16(a[i], b[j], acc[i][j], 0, 0, 0);
            __builtin_amdgcn_s_setprio(0);
        }
        __syncthreads();
    }

#pragma unroll
    for (int j = 0; j < 4; ++j) {
        const int cn = n0 + wn + j*16 + lr;
        const float bv = bias[cn];
#pragma unroll
        for (int i = 0; i < 4; ++i) {
            const int cm = m0 + wm + i*16 + lg*4;
#pragma unroll
            for (int r = 0; r < 4; ++r)
                C[(size_t)(cm + r) * N + cn] = f2b(acc[i][j][r] + bv);
        }
    }
}

__global__ void ln3_k(u16* D0, u16* D1, const u16* __restrict__ Sv,
                      const float* __restrict__ g_q, const float* __restrict__ be_q,
                      const float* __restrict__ g_k, const float* __restrict__ be_k,
                      const float* __restrict__ g_v, const float* __restrict__ be_v,
                      float* __restrict__ Vf)
{
    __shared__ float red[8];
    const int which = blockIdx.y;
    const u16* src = (which == 0) ? D0 : (which == 1) ? D1 : Sv;
    const float* g  = (which == 0) ? g_q  : (which == 1) ? g_k  : g_v;
    const float* be = (which == 0) ? be_q : (which == 1) ? be_k : be_v;
    const float scale = (which == 0) ? 0.125f * 1.4426950408889634f : 1.0f;

    const int row = blockIdx.x;
    const int tid = threadIdx.x;
    const int lane = tid & 63, wave = tid >> 6;
    ushort4 v = *(const ushort4*)&src[(size_t)row * 1024 + tid * 4];
    float f[4] = { b2f(v.x), b2f(v.y), b2f(v.z), b2f(v.w) };
    float s  = f[0] + f[1] + f[2] + f[3];
    float ss = f[0]*f[0] + f[1]*f[1] + f[2]*f[2] + f[3]*f[3];
#pragma unroll
    for (int off = 32; off; off >>= 1) { s += __shfl_down(s, off); ss += __shfl_down(ss, off); }
    if (lane == 0) { red[wave] = s; red[4 + wave] = ss; }
    __syncthreads();
    s  = red[0] + red[1] + red[2] + red[3];
    ss = red[4] + red[5] + red[6] + red[7];
    const float mean = s * (1.0f / 1024.0f);
    const float var  = fmaxf(ss * (1.0f / 1024.0f) - mean * mean, 0.0f);
    const float rs   = rsqrtf(var + 1e-5f);
    float o[4];
#pragma unroll
    for (int k = 0; k < 4; ++k) {
        const int e = tid * 4 + k;
        o[k] = ((f[k] - mean) * rs * g[e] + be[e]) * scale;
    }
    if (which == 2) {
        const int b = row >> 11, sIdx = row & 2047;
        const int h = tid >> 4, hd = (tid * 4) & 63;
        float4 ov = { o[0], o[1], o[2], o[3] };
        *(float4*)&Vf[(((size_t)(b * 16 + h) * 2048 + sIdx) << 6) + hd] = ov;
    } else {
        u16* dst = (which == 0) ? D0 : D1;
        ushort4 ov; ov.x = f2b(o[0]); ov.y = f2b(o[1]); ov.z = f2b(o[2]); ov.w = f2b(o[3]);
        *(ushort4*)&dst[(size_t)row * 1024 + tid * 4] = ov;
    }
}

__global__ void lnf_k(const u16* __restrict__ src, const float* __restrict__ g,
                      const float* __restrict__ be, float* __restrict__ dst)
{
    __shared__ float red[8];
    const int row = blockIdx.x;
    const int tid = threadIdx.x;
    const int lane = tid & 63, wave = tid >> 6;
    ushort4 v = *(const ushort4*)&src[(size_t)row * 1024 + tid * 4];
    float f[4] = { b2f(v.x), b2f(v.y), b2f(v.z), b2f(v.w) };
    float s  = f[0] + f[1] + f[2] + f[3];
    float ss = f[0]*f[0] + f[1]*f[1] + f[2]*f[2] + f[3]*f[3];
#pragma unroll
    for (int off = 32; off; off >>= 1) { s += __shfl_down(s, off); ss += __shfl_down(ss, off); }
    if (lane == 0) { red[wave] = s; red[4 + wave] = ss; }
    __syncthreads();
    s  = red[0] + red[1] + red[2] + red[3];
    ss = red[4] + red[5] + red[6] + red[7];
    const float mean = s * (1.0f / 1024.0f);
    const float var  = fmaxf(ss * (1.0f / 1024.0f) - mean * mean, 0.0f);
    const float rs   = rsqrtf(var + 1e-5f);
    float4 ov;
    ov.x = (f[0] - mean) * rs * g[tid*4+0] + be[tid*4+0];
    ov.y = (f[1] - mean) * rs * g[tid*4+1] + be[tid*4+1];
    ov.z = (f[2] - mean) * rs * g[tid*4+2] + be[tid*4+2];
    ov.w = (f[3] - mean) * rs * g[tid*4+3] + be[tid*4+3];
    *(float4*)&dst[(size_t)row * 1024 + tid * 4] = ov;
}

__global__ void vtr_k(const float* __restrict__ Vf, u16* __restrict__ Vt)
{
    __shared__ float T[64 * 65];
    const int bh = blockIdx.x >> 5, st = blockIdx.x & 31;
    const int tid = threadIdx.x;
    const float* src = Vf + (size_t)bh * 2048 * 64 + (size_t)st * 64 * 64;
#pragma unroll
    for (int it = 0; it < 4; ++it) {
        const int fid = tid + it * 256;
        const int r = fid >> 4, c4 = fid & 15;
        float4 v = *(const float4*)&src[r * 64 + c4 * 4];
        T[r * 65 + c4*4 + 0] = v.x;
        T[r * 65 + c4*4 + 1] = v.y;
        T[r * 65 + c4*4 + 2] = v.z;
        T[r * 65 + c4*4 + 3] = v.w;
    }
    __syncthreads();
    u16* dst = Vt + (size_t)bh * 64 * 2048 + (size_t)st * 64;
#pragma unroll
    for (int it = 0; it < 2; ++it) {
        const int oid = tid + it * 256;
        const int hd = oid >> 3, ch = oid & 7;
        u16 tmp[8];
#pragma unroll
        for (int j = 0; j < 8; ++j) tmp[j] = f2b(T[(ch * 8 + j) * 65 + hd]);
        const int base = 32 * (ch >> 2) + 4 * ((ch >> 1) & 1);
        const int p0 = base + 8 * ((2 * ch + 0) & 3);
        const int p1 = base + 8 * ((2 * ch + 1) & 3);
        ushort4 lo = { tmp[0], tmp[1], tmp[2], tmp[3] };
        ushort4 hi = { tmp[4], tmp[5], tmp[6], tmp[7] };
        *(ushort4*)&dst[(size_t)hd * 2048 + p0] = lo;
        *(ushort4*)&dst[(size_t)hd * 2048 + p1] = hi;
    }
}

__global__ __launch_bounds__(512, 4)
void attn_k(const u16* __restrict__ Qf, const u16* __restrict__ Kf,
            const u16* __restrict__ Vt, u16* __restrict__ O)
{
    __shared__ u16 Lds[24576];
    const int lin = (int)blockIdx.x + (int)blockIdx.y * 16;
    const int xcd = lin & 7, idx = lin >> 3;
    const int bh  = xcd * 8 + (idx & 7);
    const int qt  = 15 - (idx >> 3);
    const int b = bh >> 4, h = bh & 15;
    const int tid = threadIdx.x, wave = tid >> 6, lane = tid & 63;
    const int lg = lane >> 4, lr = lane & 15;
    const u16* Qbh = Qf + ((size_t)b * 2048) * 1024 + h * 64;
    const u16* Kbh = Kf + ((size_t)b * 2048) * 1024 + h * 64;
    const u16* Vbh = Vt + (size_t)bh * 64 * 2048;
    u16* Obh = O + ((size_t)b * 2048) * 1024 + h * 64;

    const int q0w  = qt * 128 + wave * 16;
    const int qrow = q0w + lr;
    const short8 qf0 = *(const short8*)&Qbh[(size_t)qrow * 1024 + lg * 8];
    const short8 qf1 = *(const short8*)&Qbh[(size_t)qrow * 1024 + 32 + lg * 8];

    const int nkv    = 2 * qt + 2;
    const int diagkv = q0w >> 6;

    const int kro0 = swz(lr, lg * 8) * 2;
    const int kro1 = swz(lr, 32 + lg * 8) * 2;
    const int vro0 = 8192 + kro0;
    const int vro1 = 8192 + kro1;
    const char* ldsB = (const char*)Lds;

    const int sr = tid >> 3;
    const int sc8 = ((tid & 7) ^ (sr & 7)) * 8;
    const u16* kg = Kbh + (size_t)sr * 1024 + sc8;
    const u16* vg = Vbh + (size_t)sr * 2048 + sc8;
    const int stKo = wave * 1024;

    const short s1 = (short)0x3F80;
    const short8 ones = { s1,s1,s1,s1,s1,s1,s1,s1 };

    f32x4 oacc[4] = {};
    f32x4 lacc = { 0.f, 0.f, 0.f, 0.f };

    gload16(kg,          (char*)Lds + stKo);
    gload16(vg,          (char*)Lds + 8192 + stKo);
    gload16(kg + 65536,  (char*)Lds + 16384 + stKo);
    gload16(vg + 64,     (char*)Lds + 16384 + 8192 + stKo);
    kg += 131072; vg += 128;
    VMC2;
    __builtin_amdgcn_s_barrier();

    int ro = 0;
    for (int kv = 0; kv < nkv; ++kv) {
        const bool doStage = (kv + 2 < nkv);
        if (doStage) {
            int so = ro + 32768; if (so >= 49152) so -= 49152;
            gload16(kg, (char*)Lds + so + stKo);
            gload16(vg, (char*)Lds + so + 8192 + stKo);
            kg += 65536; vg += 64;
        }

        if (kv <= diagkv) {
            const char* kp0 = ldsB + (ro + kro0);
            const char* kp1 = ldsB + (ro + kro1);

            f32x4 sacc[4];
            __builtin_amdgcn_s_setprio(1);
#pragma unroll
            for (int c = 0; c < 4; ++c) {
                const short8 k0 = *(const short8*)(kp0 + c * 2048);
                const short8 k1 = *(const short8*)(kp1 + c * 2048);
                f32x4 z = { 0.f, 0.f, 0.f, 0.f };
                z = __builtin_amdgcn_mfma_f32_16x16x32_bf16(k0, qf0, z, 0, 0, 0);
                z = __builtin_amdgcn_mfma_f32_16x16x32_bf16(k1, qf1, z, 0, 0, 0);
                sacc[c] = z;
            }
            __builtin_amdgcn_s_setprio(0);

            if (kv == diagkv) {
                const int kbase = kv * 64 + 4 * lg;
#pragma unroll
                for (int c = 0; c < 4; ++c)
#pragma unroll
                    for (int r = 0; r < 4; ++r)
                        if (kbase + c * 16 + r > qrow) sacc[c][r] = -1e30f;
            }

#pragma unroll
            for (int c = 0; c < 4; ++c)
#pragma unroll
                for (int r = 0; r < 4; ++r) sacc[c][r] = ex2(sacc[c][r]);

            const char* vp0 = ldsB + (ro + vro0);
            const char* vp1 = ldsB + (ro + vro1);
#pragma unroll
            for (int m2 = 0; m2 < 2; ++m2) {
                union { unsigned w[4]; short8 v; } pa;
                pa.w[0] = pk2(sacc[2*m2][0],   sacc[2*m2][1]);
                pa.w[1] = pk2(sacc[2*m2][2],   sacc[2*m2][3]);
                pa.w[2] = pk2(sacc[2*m2+1][0], sacc[2*m2+1][1]);
                pa.w[3] = pk2(sacc[2*m2+1][2], sacc[2*m2+1][3]);
                const char* vp = m2 ? vp1 : vp0;
                __builtin_amdgcn_s_setprio(1);
                lacc = __builtin_amdgcn_mfma_f32_16x16x32_bf16(pa.v, ones, lacc, 0, 0, 0);
#pragma unroll
                for (int c2 = 0; c2 < 4; ++c2) {
                    const short8 vb = *(const short8*)(vp + c2 * 2048);
                    oacc[c2] = __builtin_amdgcn_mfma_f32_16x16x32_bf16(pa.v, vb, oacc[c2], 0, 0, 0);
                }
                __builtin_amdgcn_s_setprio(0);
            }
        }

        if (kv + 1 < nkv) {
            if (doStage) { VMC2; }
            else        { VMC0; }
            __builtin_amdgcn_s_barrier();
        }
        ro += 16384; if (ro == 49152) ro = 0;
    }

    float lo[4];
#pragma unroll
    for (int r = 0; r < 4; ++r) lo[r] = rcp(lacc[r]);
#pragma unroll
    for (int c2 = 0; c2 < 4; ++c2)
#pragma unroll
        for (int r = 0; r < 4; ++r) {
            const float ov = oacc[c2][r] * lo[r];
            Obh[(size_t)(q0w + 4 * lg + r) * 1024 + c2 * 16 + lr] = f2b(ov);
        }
}

extern "C" void kernel_launch(void* const* d_in, const int* in_sizes, int n_in,
                              void* d_out, int out_size, void* d_ws, size_t ws_size,
                              hipStream_t stream)
{
    (void)in_sizes; (void)n_in; (void)out_size; (void)ws_size;
    const float* x   = (const float*)d_in[0];
    const float* wq  = (const float*)d_in[1];  const float* bq   = (const float*)d_in[2];
    const float* wk  = (const float*)d_in[3];  const float* bk   = (const float*)d_in[4];
    const float* wv  = (const float*)d_in[5];  const float* bv   = (const float*)d_in[6];
    const float* wp  = (const float*)d_in[7];  const float* bp   = (const float*)d_in[8];
    const float* g_q = (const float*)d_in[9];  const float* be_q = (const float*)d_in[10];
    const float* g_k = (const float*)d_in[11]; const float* be_k = (const float*)d_in[12];
    const float* g_v = (const float*)d_in[13]; const float* be_v = (const float*)d_in[14];
    const float* g_p = (const float*)d_in[15]; const float* be_p = (const float*)d_in[16];

    float* outF = (float*)d_out;
    float* Vf   = outF + 8388608;
    u16* D0 = (u16*)d_out;
    u16* D1 = (u16*)d_out + 8388608;
    u16* xb = (u16*)d_out + 16777216;
    char* ws = (char*)d_ws;
    u16* S0  = (u16*)ws;
    u16* wb  = (u16*)(ws + 16777216);
    u16* wpb = wb + 3145728;

    const dim3 bb(256);
    cvtall_k<<<dim3(12288), bb, 0, stream>>>(x, wq, wk, wv, wp, xb, wb);
    gemm3_k<<<dim3(64, 12), bb, 0, stream>>>(xb, wb, bq, bk, bv, D0, D1, S0);
    ln3_k<<<dim3(8192, 3), bb, 0, stream>>>(D0, D1, S0, g_q, be_q, g_k, be_k, g_v, be_v, Vf);
    vtr_k<<<dim3(2048), bb, 0, stream>>>(Vf, S0);
    attn_k<<<dim3(16, 64), dim3(512), 0, stream>>>(D0, D1, S0, D0);
    gemm_k<<<dim3(64, 8), bb, 0, stream>>>(D0, wpb, bp, S0, 8192, 1024, 1024);
    lnf_k<<<dim3(8192), bb, 0, stream>>>(S0, g_p, be_p, outF);
}